// Round 2
// baseline (671.210 us; speedup 1.0000x reference)
//
#include <hip/hip_runtime.h>
#include <cstdint>
#include <cstddef>

// ---------------------------------------------------------------------------
// GCN 3-layer forward on MI355X.
// Pipeline (Â = sym-normalized adjacency with self-loops; aggregation always
// on the narrower feature side since Â(XW) = (ÂX)W):
//   CSR build:  hist(dst) -> scan -> fill            (rebuilt every call)
//   t1 = X @ W1            [100k,64]
//   h1 = relu(Â t1 + b1)   [100k,64]
//   g2 = Â h1              [100k,64]
//   h2 = relu(g2 @ W2 + b2)[100k,128]
//   t3 = h2 @ W3           [100k,32]
//   out = Â t3 + b3        [100k,32]
// NOTE: edge_index arrives as int32 (harness converts integer inputs to int).
// ---------------------------------------------------------------------------

__global__ __launch_bounds__(256) void k_zero_int(int* __restrict__ p, int n) {
  int i = blockIdx.x * 256 + threadIdx.x;
  if (i < n) p[i] = 0;
}

__global__ __launch_bounds__(256) void k_hist(const int* __restrict__ dst, int E, int n,
                                              int* __restrict__ cnt) {
  int e = blockIdx.x * 256 + threadIdx.x;
  if (e >= E) return;
  int d = dst[e];
  if ((unsigned)d < (unsigned)n) atomicAdd(&cnt[d], 1);
}

// Per-block exclusive scan of cnt -> excl (local), block totals -> bsum.
// Also emits dinv = rsqrt(deg+1).
__global__ __launch_bounds__(1024) void k_scan_block(const int* __restrict__ cnt, int n,
                                                     int* __restrict__ excl,
                                                     int* __restrict__ bsum,
                                                     float* __restrict__ dinv) {
  int tid = threadIdx.x;
  int lane = tid & 63;
  int wid = tid >> 6;
  int gid = blockIdx.x * 1024 + tid;
  int v = (gid < n) ? cnt[gid] : 0;
  if (gid < n) dinv[gid] = rsqrtf((float)v + 1.0f);
  int incl = v;
#pragma unroll
  for (int o = 1; o < 64; o <<= 1) {
    int t = __shfl_up(incl, o, 64);
    if (lane >= o) incl += t;
  }
  __shared__ int wsum[16];
  if (lane == 63) wsum[wid] = incl;
  __syncthreads();
  if (wid == 0) {
    int s = (lane < 16) ? wsum[lane] : 0;
#pragma unroll
    for (int o = 1; o < 16; o <<= 1) {
      int t = __shfl_up(s, o, 64);
      if (lane >= o) s += t;
    }
    if (lane < 16) wsum[lane] = s;
  }
  __syncthreads();
  int off = wid ? wsum[wid - 1] : 0;
  if (gid < n) excl[gid] = off + incl - v;
  if (tid == 1023) bsum[blockIdx.x] = wsum[15];
}

// Single-block exclusive scan of block sums (B <= 128).
__global__ __launch_bounds__(128) void k_scan_top(const int* __restrict__ bsum,
                                                  int* __restrict__ boff, int B) {
  __shared__ int sm[128];
  int tid = threadIdx.x;
  int v = (tid < B) ? bsum[tid] : 0;
  sm[tid] = v;
  __syncthreads();
  for (int o = 1; o < 128; o <<= 1) {
    int t = (tid >= o) ? sm[tid - o] : 0;
    __syncthreads();
    sm[tid] += t;
    __syncthreads();
  }
  if (tid < B) boff[tid] = sm[tid] - v;
}

__global__ __launch_bounds__(256) void k_scan_add(int* __restrict__ rowptr,
                                                  const int* __restrict__ boff, int n, int E) {
  int i = blockIdx.x * 256 + threadIdx.x;
  if (i < n)
    rowptr[i] += boff[i >> 10];
  else if (i == n)
    rowptr[n] = E;
}

__global__ __launch_bounds__(256) void k_fill(const int* __restrict__ src,
                                              const int* __restrict__ dst, int E, int n,
                                              const int* __restrict__ rowptr,
                                              int* __restrict__ fill,
                                              int* __restrict__ col) {
  int e = blockIdx.x * 256 + threadIdx.x;
  if (e >= E) return;
  int s = src[e];
  int d = dst[e];
  if ((unsigned)d >= (unsigned)n || (unsigned)s >= (unsigned)n) return;  // mirror k_hist skip
  int p = atomicAdd(&fill[d], 1);
  col[rowptr[d] + p] = s;
}

// Dense GEMM: Y[n,F] = X[n,K] @ W[K,F] (+bias, +relu). Thread per (row, f-chunk).
// W access is wave-uniform -> scalar loads feeding v_fmac with SGPR operand.
template <int K, int FCHUNK, int F, bool RELU, bool BIAS>
__global__ __launch_bounds__(256) void k_gemm(const float* __restrict__ X,
                                              const float* __restrict__ W,
                                              const float* __restrict__ bias,
                                              float* __restrict__ Y, int n) {
  int row = blockIdx.x * 256 + threadIdx.x;
  int f0 = blockIdx.y * FCHUNK;
  if (row >= n) return;
  float acc[FCHUNK];
#pragma unroll
  for (int f = 0; f < FCHUNK; ++f) acc[f] = 0.0f;
  const float* xr = X + (size_t)row * K;
  for (int k = 0; k < K; k += 4) {
    float4 xv = *reinterpret_cast<const float4*>(xr + k);
#pragma unroll
    for (int j = 0; j < 4; ++j) {
      float xk = (&xv.x)[j];
#pragma unroll
      for (int f = 0; f < FCHUNK; ++f) acc[f] += xk * W[(size_t)(k + j) * F + f0 + f];
    }
  }
#pragma unroll
  for (int f = 0; f < FCHUNK; ++f) {
    float a = acc[f];
    if (BIAS) a += bias[f0 + f];
    if (RELU) a = fmaxf(a, 0.0f);
    acc[f] = a;
  }
  float4* yo = reinterpret_cast<float4*>(Y + (size_t)row * F + f0);
#pragma unroll
  for (int f4 = 0; f4 < FCHUNK / 4; ++f4)
    yo[f4] = make_float4(acc[4 * f4], acc[4 * f4 + 1], acc[4 * f4 + 2], acc[4 * f4 + 3]);
}

// CSR gather-aggregate: Y[i] = sum_{s in N(i)} T[s]*dinv[s]*dinv[i] + T[i]*dinv[i]^2 (+b, relu)
// One 64/F-node group per wave; lane = feature. col/dinv loads are wave-uniform for F=64.
template <int F, bool RELU, bool BIAS>
__global__ __launch_bounds__(256) void k_agg(const float* __restrict__ T,
                                             const int* __restrict__ rowptr,
                                             const int* __restrict__ col,
                                             const float* __restrict__ dinv,
                                             const float* __restrict__ bias,
                                             float* __restrict__ Y, int n) {
  constexpr int GPW = 64 / F;  // node groups per wave
  int lane = threadIdx.x & 63;
  int wid = threadIdx.x >> 6;
  int g = lane / F;
  int f = lane % F;
  int node = (blockIdx.x * (int)(blockDim.x >> 6) + wid) * GPW + g;
  if (node >= n) return;
  int base = rowptr[node];
  int end = rowptr[node + 1];
  float di = dinv[node];
  float acc = T[(size_t)node * F + f] * di * di;
  if (BIAS) acc += bias[f];
  int j = base;
  // unroll by 2 for a bit of MLP
  for (; j + 1 < end; j += 2) {
    int s0 = col[j];
    int s1 = col[j + 1];
    float w0 = dinv[s0] * di;
    float w1 = dinv[s1] * di;
    acc += T[(size_t)s0 * F + f] * w0;
    acc += T[(size_t)s1 * F + f] * w1;
  }
  if (j < end) {
    int s0 = col[j];
    acc += T[(size_t)s0 * F + f] * (dinv[s0] * di);
  }
  if (RELU) acc = fmaxf(acc, 0.0f);
  Y[(size_t)node * F + f] = acc;
}

extern "C" void kernel_launch(void* const* d_in, const int* in_sizes, int n_in,
                              void* d_out, int out_size, void* d_ws, size_t ws_size,
                              hipStream_t stream) {
  const float* x = (const float*)d_in[0];
  const int* eidx = (const int*)d_in[1];  // int32: [2,E] flattened (src row, dst row)
  const float* W1 = (const float*)d_in[2];
  const float* b1 = (const float*)d_in[3];
  const float* W2 = (const float*)d_in[4];
  const float* b2 = (const float*)d_in[5];
  const float* W3 = (const float*)d_in[6];
  const float* b3 = (const float*)d_in[7];
  float* out = (float*)d_out;

  const int n = in_sizes[0] / 128;  // 100000 nodes
  const int E = in_sizes[1] / 2;    // 1.6M edges
  const int* esrc = eidx;
  const int* edst = eidx + E;

  // bump allocator over d_ws (re-poisoned every call; all buffers fully rewritten)
  size_t off = 0;
  auto alloc = [&](size_t bytes) {
    size_t o = off;
    off = (off + bytes + 511) & ~(size_t)511;
    return (char*)d_ws + o;
  };
  int* cnt = (int*)alloc((size_t)n * 4);
  int* fill = (int*)alloc((size_t)n * 4);
  int* bsum = (int*)alloc(128 * 4);
  int* boff = (int*)alloc(128 * 4);
  int* rowptr = (int*)alloc((size_t)(n + 1) * 4);
  float* dinv = (float*)alloc((size_t)n * 4);
  int* col = (int*)alloc((size_t)E * 4);
  float* bufA = (float*)alloc((size_t)n * 64 * 4);   // t1 -> g2 -> t3
  float* bufB = (float*)alloc((size_t)n * 64 * 4);   // h1
  float* bufC = (float*)alloc((size_t)n * 128 * 4);  // h2
  if (off > ws_size) return;  // ws too small: leave d_out poisoned (visible failure, no fault)

  const int B = (n + 1023) / 1024;  // scan blocks (98 <= 128)

  // --- CSR build ---
  hipLaunchKernelGGL(k_zero_int, dim3((n + 255) / 256), dim3(256), 0, stream, cnt, n);
  hipLaunchKernelGGL(k_zero_int, dim3((n + 255) / 256), dim3(256), 0, stream, fill, n);
  hipLaunchKernelGGL(k_hist, dim3((E + 255) / 256), dim3(256), 0, stream, edst, E, n, cnt);
  hipLaunchKernelGGL(k_scan_block, dim3(B), dim3(1024), 0, stream, cnt, n, rowptr, bsum, dinv);
  hipLaunchKernelGGL(k_scan_top, dim3(1), dim3(128), 0, stream, bsum, boff, B);
  hipLaunchKernelGGL(k_scan_add, dim3((n + 1 + 255) / 256), dim3(256), 0, stream, rowptr, boff, n, E);
  hipLaunchKernelGGL(k_fill, dim3((E + 255) / 256), dim3(256), 0, stream, esrc, edst, E, n, rowptr,
                     fill, col);

  // --- layer 1: t1 = X@W1 ; h1 = relu(Â t1 + b1) ---
  hipLaunchKernelGGL((k_gemm<128, 64, 64, false, false>), dim3((n + 255) / 256, 1), dim3(256), 0,
                     stream, x, W1, nullptr, bufA, n);
  hipLaunchKernelGGL((k_agg<64, true, true>), dim3((n + 3) / 4), dim3(256), 0, stream, bufA,
                     rowptr, col, dinv, b1, bufB, n);

  // --- layer 2: g2 = Â h1 ; h2 = relu(g2@W2 + b2) ---
  hipLaunchKernelGGL((k_agg<64, false, false>), dim3((n + 3) / 4), dim3(256), 0, stream, bufB,
                     rowptr, col, dinv, nullptr, bufA, n);
  hipLaunchKernelGGL((k_gemm<64, 64, 128, true, true>), dim3((n + 255) / 256, 2), dim3(256), 0,
                     stream, bufA, W2, b2, bufC, n);

  // --- layer 3: t3 = h2@W3 ; out = Â t3 + b3 ---
  hipLaunchKernelGGL((k_gemm<128, 32, 32, false, false>), dim3((n + 255) / 256, 1), dim3(256), 0,
                     stream, bufC, W3, nullptr, bufA, n);
  hipLaunchKernelGGL((k_agg<32, false, true>), dim3((n + 7) / 8), dim3(256), 0, stream, bufA,
                     rowptr, col, dinv, b3, out, n);

  (void)n_in;
  (void)out_size;
}

// Round 4
// 584.901 us; speedup vs baseline: 1.1476x; 1.1476x over previous
//
#include <hip/hip_runtime.h>
#include <cstdint>
#include <cstddef>

// ---------------------------------------------------------------------------
// GCN 3-layer forward on MI355X.
//   Â = D^-1/2 (A+I) D^-1/2, aggregation on the narrower side (Â(XW)=(ÂX)W):
//   memset cnt=0
//   [fused] rank[e]=atomicAdd(cnt[dst[e]]) ∥ t1 = X@W1       (independent work)
//   scan cnt -> rowptr, dinv
//   place: col[rowptr[d]+rank[e]] = src[e]                   (no atomics)
//   h1 = relu(Â t1 + b1); g2 = Â h1; h2 = relu(g2@W2 + b2)
//   t3 = h2@W3; out = Â t3 + b3
// Evidence base (round 2 rocprof): global atomics write-through 64B/op to HBM
// (k_fill WRITE_SIZE 107MB, 125 µs, VALUBusy 0.5%) -> halve atomic passes and
// overlap the remaining one with VALU-bound GEMM1.
// ---------------------------------------------------------------------------

// Per-block exclusive scan of cnt -> rowptr (local), block totals -> bsum.
// Also emits dinv = rsqrt(deg+1).
__global__ __launch_bounds__(1024) void k_scan_block(const int* __restrict__ cnt, int n,
                                                     int* __restrict__ excl,
                                                     int* __restrict__ bsum,
                                                     float* __restrict__ dinv) {
  int tid = threadIdx.x;
  int lane = tid & 63;
  int wid = tid >> 6;
  int gid = blockIdx.x * 1024 + tid;
  int v = (gid < n) ? cnt[gid] : 0;
  if (gid < n) dinv[gid] = rsqrtf((float)v + 1.0f);
  int incl = v;
#pragma unroll
  for (int o = 1; o < 64; o <<= 1) {
    int t = __shfl_up(incl, o, 64);
    if (lane >= o) incl += t;
  }
  __shared__ int wsum[16];
  if (lane == 63) wsum[wid] = incl;
  __syncthreads();
  if (wid == 0) {
    int s = (lane < 16) ? wsum[lane] : 0;
#pragma unroll
    for (int o = 1; o < 16; o <<= 1) {
      int t = __shfl_up(s, o, 64);
      if (lane >= o) s += t;
    }
    if (lane < 16) wsum[lane] = s;
  }
  __syncthreads();
  int off = wid ? wsum[wid - 1] : 0;
  if (gid < n) excl[gid] = off + incl - v;
  if (tid == 1023) bsum[blockIdx.x] = wsum[15];
}

__global__ __launch_bounds__(128) void k_scan_top(const int* __restrict__ bsum,
                                                  int* __restrict__ boff, int B) {
  __shared__ int sm[128];
  int tid = threadIdx.x;
  int v = (tid < B) ? bsum[tid] : 0;
  sm[tid] = v;
  __syncthreads();
  for (int o = 1; o < 128; o <<= 1) {
    int t = (tid >= o) ? sm[tid - o] : 0;
    __syncthreads();
    sm[tid] += t;
    __syncthreads();
  }
  if (tid < B) boff[tid] = sm[tid] - v;
}

__global__ __launch_bounds__(256) void k_scan_add(int* __restrict__ rowptr,
                                                  const int* __restrict__ boff, int n, int E) {
  int i = blockIdx.x * 256 + threadIdx.x;
  if (i < n)
    rowptr[i] += boff[i >> 10];
  else if (i == n)
    rowptr[n] = E;
}

// Dense GEMM body: Y[n,F] = X[n,K] @ W[K,F] (+bias, +relu). Thread per row.
// W access is wave-uniform-ish; acc lives in VGPRs.
template <int K, int FCHUNK, int F, bool RELU, bool BIAS>
__device__ inline void gemm_body(const float* __restrict__ X, const float* __restrict__ W,
                                 const float* __restrict__ bias, float* __restrict__ Y, int n,
                                 int row, int f0) {
  if (row >= n) return;
  float acc[FCHUNK];
#pragma unroll
  for (int f = 0; f < FCHUNK; ++f) acc[f] = 0.0f;
  const float* xr = X + (size_t)row * K;
  for (int k = 0; k < K; k += 4) {
    float4 xv = *reinterpret_cast<const float4*>(xr + k);
#pragma unroll
    for (int j = 0; j < 4; ++j) {
      float xk = (&xv.x)[j];
#pragma unroll
      for (int f = 0; f < FCHUNK; ++f) acc[f] += xk * W[(size_t)(k + j) * F + f0 + f];
    }
  }
#pragma unroll
  for (int f = 0; f < FCHUNK; ++f) {
    float a = acc[f];
    if (BIAS) a += bias[f0 + f];
    if (RELU) a = fmaxf(a, 0.0f);
    acc[f] = a;
  }
  float4* yo = reinterpret_cast<float4*>(Y + (size_t)row * F + f0);
#pragma unroll
  for (int f4 = 0; f4 < FCHUNK / 4; ++f4)
    yo[f4] = make_float4(acc[4 * f4], acc[4 * f4 + 1], acc[4 * f4 + 2], acc[4 * f4 + 3]);
}

template <int K, int FCHUNK, int F, bool RELU, bool BIAS>
__global__ __launch_bounds__(256) void k_gemm(const float* __restrict__ X,
                                              const float* __restrict__ W,
                                              const float* __restrict__ bias,
                                              float* __restrict__ Y, int n) {
  gemm_body<K, FCHUNK, F, RELU, BIAS>(X, W, bias, Y, n, blockIdx.x * 256 + threadIdx.x,
                                      blockIdx.y * FCHUNK);
}

// Fused: blocks with bid%5<4 do the atomic rank pass (4 edges/thread, int4),
// blocks with bid%5==4 run GEMM1. Latency-bound atomics hide VALU-bound GEMM.
template <int K, int FCHUNK, int F>
__global__ __launch_bounds__(256) void k_rank_gemm(const int* __restrict__ edst, int E, int n,
                                                   int* __restrict__ cnt, int* __restrict__ rank,
                                                   const float* __restrict__ X,
                                                   const float* __restrict__ W,
                                                   float* __restrict__ Y) {
  int bid = blockIdx.x;
  int r = bid % 5;
  if (r < 4) {
    int rb = (bid / 5) * 4 + r;
    int e0 = (rb * 256 + (int)threadIdx.x) * 4;
    if (e0 + 3 < E) {
      int4 d4 = *reinterpret_cast<const int4*>(edst + e0);
      int4 rk;
      rk.x = atomicAdd(&cnt[d4.x], 1);
      rk.y = atomicAdd(&cnt[d4.y], 1);
      rk.z = atomicAdd(&cnt[d4.z], 1);
      rk.w = atomicAdd(&cnt[d4.w], 1);
      *reinterpret_cast<int4*>(rank + e0) = rk;
    } else {
      for (int j = 0; j < 4; ++j)
        if (e0 + j < E) rank[e0 + j] = atomicAdd(&cnt[edst[e0 + j]], 1);
    }
  } else {
    gemm_body<K, FCHUNK, F, false, false>(X, W, nullptr, Y, n, (bid / 5) * 256 + (int)threadIdx.x,
                                          0);
  }
}

// Non-atomic placement: col[rowptr[d]+rank[e]] = s. Scattered 4B writes, L2-resident.
__global__ __launch_bounds__(256) void k_place(const int* __restrict__ esrc,
                                               const int* __restrict__ edst,
                                               const int* __restrict__ rank, int E,
                                               const int* __restrict__ rowptr,
                                               int* __restrict__ col) {
  int e0 = (blockIdx.x * 256 + (int)threadIdx.x) * 4;
  if (e0 + 3 < E) {
    int4 s4 = *reinterpret_cast<const int4*>(esrc + e0);
    int4 d4 = *reinterpret_cast<const int4*>(edst + e0);
    int4 r4 = *reinterpret_cast<const int4*>(rank + e0);
    col[rowptr[d4.x] + r4.x] = s4.x;
    col[rowptr[d4.y] + r4.y] = s4.y;
    col[rowptr[d4.z] + r4.z] = s4.z;
    col[rowptr[d4.w] + r4.w] = s4.w;
  } else {
    for (int j = 0; j < 4; ++j)
      if (e0 + j < E) col[rowptr[edst[e0 + j]] + rank[e0 + j]] = esrc[e0 + j];
  }
}

// CSR gather-aggregate: Y[i] = sum_{s in N(i)} T[s]*dinv[s]*dinv[i] + T[i]*dinv[i]^2 (+b, relu)
template <int F, bool RELU, bool BIAS>
__global__ __launch_bounds__(256) void k_agg(const float* __restrict__ T,
                                             const int* __restrict__ rowptr,
                                             const int* __restrict__ col,
                                             const float* __restrict__ dinv,
                                             const float* __restrict__ bias,
                                             float* __restrict__ Y, int n) {
  constexpr int GPW = 64 / F;  // node groups per wave
  int lane = threadIdx.x & 63;
  int wid = threadIdx.x >> 6;
  int g = lane / F;
  int f = lane % F;
  int node = (blockIdx.x * (int)(blockDim.x >> 6) + wid) * GPW + g;
  if (node >= n) return;
  int base = rowptr[node];
  int end = rowptr[node + 1];
  float di = dinv[node];
  float acc = T[(size_t)node * F + f] * di * di;
  if (BIAS) acc += bias[f];
  int j = base;
  for (; j + 1 < end; j += 2) {
    int s0 = col[j];
    int s1 = col[j + 1];
    float w0 = dinv[s0] * di;
    float w1 = dinv[s1] * di;
    acc += T[(size_t)s0 * F + f] * w0;
    acc += T[(size_t)s1 * F + f] * w1;
  }
  if (j < end) {
    int s0 = col[j];
    acc += T[(size_t)s0 * F + f] * (dinv[s0] * di);
  }
  if (RELU) acc = fmaxf(acc, 0.0f);
  Y[(size_t)node * F + f] = acc;
}

extern "C" void kernel_launch(void* const* d_in, const int* in_sizes, int n_in,
                              void* d_out, int out_size, void* d_ws, size_t ws_size,
                              hipStream_t stream) {
  const float* x = (const float*)d_in[0];
  const int* eidx = (const int*)d_in[1];  // int32: [2,E] flattened (src row, dst row)
  const float* W1 = (const float*)d_in[2];
  const float* b1 = (const float*)d_in[3];
  const float* W2 = (const float*)d_in[4];
  const float* b2 = (const float*)d_in[5];
  const float* W3 = (const float*)d_in[6];
  const float* b3 = (const float*)d_in[7];
  float* out = (float*)d_out;

  const int n = in_sizes[0] / 128;  // 100000 nodes
  const int E = in_sizes[1] / 2;    // 1.6M edges
  const int* esrc = eidx;
  const int* edst = eidx + E;

  // bump allocator over d_ws (re-poisoned every call; all buffers fully rewritten)
  size_t off = 0;
  auto alloc = [&](size_t bytes) {
    size_t o = off;
    off = (off + bytes + 511) & ~(size_t)511;
    return (char*)d_ws + o;
  };
  int* cnt = (int*)alloc((size_t)n * 4);
  int* bsum = (int*)alloc(128 * 4);
  int* boff = (int*)alloc(128 * 4);
  int* rowptr = (int*)alloc((size_t)(n + 1) * 4);
  float* dinv = (float*)alloc((size_t)n * 4);
  int* col = (int*)alloc((size_t)E * 4);
  float* bufA = (float*)alloc((size_t)n * 64 * 4);   // t1 -> g2 -> t3
  float* bufB = (float*)alloc((size_t)n * 64 * 4);   // h1
  float* bufC = (float*)alloc((size_t)n * 128 * 4);  // h2
  int* rank = (int*)bufC;  // lifetime-disjoint overlay: rank dies before gemm2 writes h2
  if (off > ws_size) return;  // visible failure (poisoned d_out), no fault

  const int B = (n + 1023) / 1024;  // scan blocks (98 <= 128)
  const int rankBlocks = (E + 1023) / 1024;         // 4 edges/thread
  const int gemmBlocks = (n + 255) / 256;           // 1 row/thread
  int fusedGrid = 5 * ((rankBlocks + 3) / 4);
  if (5 * gemmBlocks > fusedGrid) fusedGrid = 5 * gemmBlocks;

  // --- CSR build (pass 1) fused with GEMM1 ---
  hipMemsetAsync(cnt, 0, (size_t)n * 4, stream);
  hipLaunchKernelGGL((k_rank_gemm<128, 64, 64>), dim3(fusedGrid), dim3(256), 0, stream, edst, E,
                     n, cnt, rank, x, W1, bufA);
  hipLaunchKernelGGL(k_scan_block, dim3(B), dim3(1024), 0, stream, cnt, n, rowptr, bsum, dinv);
  hipLaunchKernelGGL(k_scan_top, dim3(1), dim3(128), 0, stream, bsum, boff, B);
  hipLaunchKernelGGL(k_scan_add, dim3((n + 1 + 255) / 256), dim3(256), 0, stream, rowptr, boff, n, E);
  hipLaunchKernelGGL(k_place, dim3((E + 1023) / 1024), dim3(256), 0, stream, esrc, edst, rank, E,
                     rowptr, col);

  // --- layer 1 aggregation: h1 = relu(Â t1 + b1) ---
  hipLaunchKernelGGL((k_agg<64, true, true>), dim3((n + 3) / 4), dim3(256), 0, stream, bufA,
                     rowptr, col, dinv, b1, bufB, n);

  // --- layer 2: g2 = Â h1 ; h2 = relu(g2@W2 + b2) ---
  hipLaunchKernelGGL((k_agg<64, false, false>), dim3((n + 3) / 4), dim3(256), 0, stream, bufB,
                     rowptr, col, dinv, nullptr, bufA, n);
  hipLaunchKernelGGL((k_gemm<64, 64, 128, true, true>), dim3((n + 255) / 256, 2), dim3(256), 0,
                     stream, bufA, W2, b2, bufC, n);

  // --- layer 3: t3 = h2@W3 ; out = Â t3 + b3 ---
  hipLaunchKernelGGL((k_gemm<128, 32, 32, false, false>), dim3((n + 255) / 256, 1), dim3(256), 0,
                     stream, bufC, W3, nullptr, bufA, n);
  hipLaunchKernelGGL((k_agg<32, false, true>), dim3((n + 7) / 8), dim3(256), 0, stream, bufA,
                     rowptr, col, dinv, b3, out, n);

  (void)n_in;
  (void)out_size;
}

// Round 9
// 544.286 us; speedup vs baseline: 1.2332x; 1.0746x over previous
//
#include <hip/hip_runtime.h>
#include <cstdint>
#include <cstddef>

// ---------------------------------------------------------------------------
// GCN 3-layer forward on MI355X.
//   Â = D^-1/2 (A+I) D^-1/2, aggregation on the narrower side (Â(XW)=(ÂX)W):
//   memset cnt=0
//   [fused] rank[e]=atomicAdd(cnt[dst[e]]) ∥ t1 = X@W1       (4:2 block interleave)
//   scan cnt -> rowptr, dinv
//   place: col[rowptr[d]+rank[e]] = src[e]                   (no atomics)
//   h1 = relu(Â t1 + b1); g2 = Â h1; h2 = relu(g2@W2 + b2)
//   t3 = h2@W3; out = Â t3 + b3
// Round-4 evidence: VGPR_Count=40 on rank_gemm => acc[64] spilled to scratch
// (fix: FCHUNK=32). Aggs ~latency-bound at MLP 2 (fix: shfl-batched edges,
// 8 T-row gathers in flight).
// ---------------------------------------------------------------------------

// Per-block exclusive scan of cnt -> rowptr (local), block totals -> bsum.
// Also emits dinv = rsqrt(deg+1).
__global__ __launch_bounds__(1024) void k_scan_block(const int* __restrict__ cnt, int n,
                                                     int* __restrict__ excl,
                                                     int* __restrict__ bsum,
                                                     float* __restrict__ dinv) {
  int tid = threadIdx.x;
  int lane = tid & 63;
  int wid = tid >> 6;
  int gid = blockIdx.x * 1024 + tid;
  int v = (gid < n) ? cnt[gid] : 0;
  if (gid < n) dinv[gid] = rsqrtf((float)v + 1.0f);
  int incl = v;
#pragma unroll
  for (int o = 1; o < 64; o <<= 1) {
    int t = __shfl_up(incl, o, 64);
    if (lane >= o) incl += t;
  }
  __shared__ int wsum[16];
  if (lane == 63) wsum[wid] = incl;
  __syncthreads();
  if (wid == 0) {
    int s = (lane < 16) ? wsum[lane] : 0;
#pragma unroll
    for (int o = 1; o < 16; o <<= 1) {
      int t = __shfl_up(s, o, 64);
      if (lane >= o) s += t;
    }
    if (lane < 16) wsum[lane] = s;
  }
  __syncthreads();
  int off = wid ? wsum[wid - 1] : 0;
  if (gid < n) excl[gid] = off + incl - v;
  if (tid == 1023) bsum[blockIdx.x] = wsum[15];
}

__global__ __launch_bounds__(128) void k_scan_top(const int* __restrict__ bsum,
                                                  int* __restrict__ boff, int B) {
  __shared__ int sm[128];
  int tid = threadIdx.x;
  int v = (tid < B) ? bsum[tid] : 0;
  sm[tid] = v;
  __syncthreads();
  for (int o = 1; o < 128; o <<= 1) {
    int t = (tid >= o) ? sm[tid - o] : 0;
    __syncthreads();
    sm[tid] += t;
    __syncthreads();
  }
  if (tid < B) boff[tid] = sm[tid] - v;
}

__global__ __launch_bounds__(256) void k_scan_add(int* __restrict__ rowptr,
                                                  const int* __restrict__ boff, int n, int E) {
  int i = blockIdx.x * 256 + threadIdx.x;
  if (i < n)
    rowptr[i] += boff[i >> 10];
  else if (i == n)
    rowptr[n] = E;
}

// Dense GEMM body, FCHUNK=32 (acc[32] stays in VGPRs; round-4 showed FCHUNK=64
// spilled to scratch: VGPR_Count=40 < 64 accumulators).
template <int K, int F, bool RELU, bool BIAS>
__device__ inline void gemm_body32(const float* __restrict__ X, const float* __restrict__ W,
                                   const float* __restrict__ bias, float* __restrict__ Y, int n,
                                   int row, int f0) {
  if (row >= n) return;
  float acc[32];
#pragma unroll
  for (int f = 0; f < 32; ++f) acc[f] = 0.0f;
  const float* xr = X + (size_t)row * K;
  for (int k = 0; k < K; k += 4) {
    float4 xv = *reinterpret_cast<const float4*>(xr + k);
#pragma unroll
    for (int j = 0; j < 4; ++j) {
      float xk = (&xv.x)[j];
#pragma unroll
      for (int f = 0; f < 32; ++f) acc[f] += xk * W[(size_t)(k + j) * F + f0 + f];
    }
  }
#pragma unroll
  for (int f = 0; f < 32; ++f) {
    float a = acc[f];
    if (BIAS) a += bias[f0 + f];
    if (RELU) a = fmaxf(a, 0.0f);
    acc[f] = a;
  }
  float4* yo = reinterpret_cast<float4*>(Y + (size_t)row * F + f0);
#pragma unroll
  for (int f4 = 0; f4 < 8; ++f4)
    yo[f4] = make_float4(acc[4 * f4], acc[4 * f4 + 1], acc[4 * f4 + 2], acc[4 * f4 + 3]);
}

template <int K, int F, bool RELU, bool BIAS>
__global__ __launch_bounds__(256) void k_gemm(const float* __restrict__ X,
                                              const float* __restrict__ W,
                                              const float* __restrict__ bias,
                                              float* __restrict__ Y, int n) {
  gemm_body32<K, F, RELU, BIAS>(X, W, bias, Y, n, blockIdx.x * 256 + threadIdx.x,
                                blockIdx.y * 32);
}

// Fused: period-6 block interleave. r<4: atomic rank pass (4 edges/thread, int4);
// r>=4: GEMM1 f-chunk task. Latency/write-bound atomics hide VALU-bound GEMM.
// At E=1.6M, n=100k both sides need exactly ceil(1563/4)=ceil(782/2)=391 periods.
template <int K, int F>
__global__ __launch_bounds__(256) void k_rank_gemm(const int* __restrict__ edst, int E, int n,
                                                   int* __restrict__ cnt, int* __restrict__ rank,
                                                   const float* __restrict__ X,
                                                   const float* __restrict__ W,
                                                   float* __restrict__ Y) {
  int bid = blockIdx.x;
  int r = bid % 6;
  int p = bid / 6;
  if (r < 4) {
    int rb = p * 4 + r;
    int e0 = (rb * 256 + (int)threadIdx.x) * 4;
    if (e0 + 3 < E) {
      int4 d4 = *reinterpret_cast<const int4*>(edst + e0);
      int4 rk;
      rk.x = atomicAdd(&cnt[d4.x], 1);
      rk.y = atomicAdd(&cnt[d4.y], 1);
      rk.z = atomicAdd(&cnt[d4.z], 1);
      rk.w = atomicAdd(&cnt[d4.w], 1);
      *reinterpret_cast<int4*>(rank + e0) = rk;
    } else {
      for (int j = 0; j < 4; ++j)
        if (e0 + j < E) rank[e0 + j] = atomicAdd(&cnt[edst[e0 + j]], 1);
    }
  } else {
    int gtask = p * 2 + (r - 4);  // [0, 2*ceil(n/256))
    gemm_body32<K, F, false, false>(X, W, nullptr, Y, n, (gtask >> 1) * 256 + (int)threadIdx.x,
                                    (gtask & 1) * 32);
  }
}

// Non-atomic placement: col[rowptr[d]+rank[e]] = s. Scattered 4B writes, L2-resident.
__global__ __launch_bounds__(256) void k_place(const int* __restrict__ esrc,
                                               const int* __restrict__ edst,
                                               const int* __restrict__ rank, int E,
                                               const int* __restrict__ rowptr,
                                               int* __restrict__ col) {
  int e0 = (blockIdx.x * 256 + (int)threadIdx.x) * 4;
  if (e0 + 3 < E) {
    int4 s4 = *reinterpret_cast<const int4*>(esrc + e0);
    int4 d4 = *reinterpret_cast<const int4*>(edst + e0);
    int4 r4 = *reinterpret_cast<const int4*>(rank + e0);
    col[rowptr[d4.x] + r4.x] = s4.x;
    col[rowptr[d4.y] + r4.y] = s4.y;
    col[rowptr[d4.z] + r4.z] = s4.z;
    col[rowptr[d4.w] + r4.w] = s4.w;
  } else {
    for (int j = 0; j < 4; ++j)
      if (e0 + j < E) col[rowptr[edst[e0 + j]] + rank[e0 + j]] = esrc[e0 + j];
  }
}

// CSR gather-aggregate, MLP-8 version.
// Group of F lanes owns one node. Per chunk of <=F edges: ONE coalesced col
// load + parallel dinv gather across lanes, then shfl-broadcast and keep 8
// T-row gathers in flight. Tail slots use s=0/w=0 (reads row 0, contributes 0).
template <int F, bool RELU, bool BIAS>
__global__ __launch_bounds__(256) void k_agg(const float* __restrict__ T,
                                             const int* __restrict__ rowptr,
                                             const int* __restrict__ col,
                                             const float* __restrict__ dinv,
                                             const float* __restrict__ bias,
                                             float* __restrict__ Y, int n) {
  constexpr int GPW = 64 / F;  // node groups per wave
  int lane = threadIdx.x & 63;
  int wid = threadIdx.x >> 6;
  int g = lane / F;
  int f = lane % F;
  int node = (blockIdx.x * (int)(blockDim.x >> 6) + wid) * GPW + g;
  if (node >= n) return;  // whole F-lane group exits together (node depends on g only)
  int base = rowptr[node];
  int deg = rowptr[node + 1] - base;
  float di = dinv[node];
  float acc = T[(size_t)node * F + f] * di * di;
  if (BIAS) acc += bias[f];
  for (int c0 = 0; c0 < deg; c0 += F) {
    int cc = deg - c0;
    if (cc > F) cc = F;
    int myS = 0;
    float myW = 0.0f;
    if (f < cc) {
      myS = col[base + c0 + f];    // coalesced across the group
      myW = dinv[myS] * di;        // parallel gather across lanes
    }
    for (int i = 0; i < cc; i += 8) {
      int ss[8];
      float ww[8];
      float vv[8];
#pragma unroll
      for (int k = 0; k < 8; ++k) {
        ss[k] = __shfl(myS, i + k, F);  // lanes >= cc hold s=0/w=0
        ww[k] = __shfl(myW, i + k, F);
      }
#pragma unroll
      for (int k = 0; k < 8; ++k) vv[k] = T[(size_t)ss[k] * F + f];  // 8 gathers in flight
#pragma unroll
      for (int k = 0; k < 8; ++k) acc += vv[k] * ww[k];
    }
  }
  if (RELU) acc = fmaxf(acc, 0.0f);
  Y[(size_t)node * F + f] = acc;
}

extern "C" void kernel_launch(void* const* d_in, const int* in_sizes, int n_in,
                              void* d_out, int out_size, void* d_ws, size_t ws_size,
                              hipStream_t stream) {
  const float* x = (const float*)d_in[0];
  const int* eidx = (const int*)d_in[1];  // int32: [2,E] flattened (src row, dst row)
  const float* W1 = (const float*)d_in[2];
  const float* b1 = (const float*)d_in[3];
  const float* W2 = (const float*)d_in[4];
  const float* b2 = (const float*)d_in[5];
  const float* W3 = (const float*)d_in[6];
  const float* b3 = (const float*)d_in[7];
  float* out = (float*)d_out;

  const int n = in_sizes[0] / 128;  // 100000 nodes
  const int E = in_sizes[1] / 2;    // 1.6M edges
  const int* esrc = eidx;
  const int* edst = eidx + E;

  // bump allocator over d_ws (re-poisoned every call; all buffers fully rewritten)
  size_t off = 0;
  auto alloc = [&](size_t bytes) {
    size_t o = off;
    off = (off + bytes + 511) & ~(size_t)511;
    return (char*)d_ws + o;
  };
  int* cnt = (int*)alloc((size_t)n * 4);
  int* bsum = (int*)alloc(128 * 4);
  int* boff = (int*)alloc(128 * 4);
  int* rowptr = (int*)alloc((size_t)(n + 1) * 4);
  float* dinv = (float*)alloc((size_t)n * 4);
  int* col = (int*)alloc((size_t)E * 4);
  float* bufA = (float*)alloc((size_t)n * 64 * 4);   // t1 -> g2 -> t3
  float* bufB = (float*)alloc((size_t)n * 64 * 4);   // h1
  float* bufC = (float*)alloc((size_t)n * 128 * 4);  // h2
  int* rank = (int*)bufC;  // lifetime-disjoint overlay: rank dies before gemm2 writes h2
  if (off > ws_size) return;  // visible failure (poisoned d_out), no fault

  const int B = (n + 1023) / 1024;            // scan blocks (98 <= 128)
  const int rankBlocks = (E + 1023) / 1024;   // 4 edges/thread
  const int gemmTasks = ((n + 255) / 256) * 2;  // 2 f-chunks of 32 for F=64
  int periods = (rankBlocks + 3) / 4;
  if ((gemmTasks + 1) / 2 > periods) periods = (gemmTasks + 1) / 2;
  const int fusedGrid = 6 * periods;

  // --- CSR build (pass 1) fused with GEMM1 ---
  hipMemsetAsync(cnt, 0, (size_t)n * 4, stream);
  hipLaunchKernelGGL((k_rank_gemm<128, 64>), dim3(fusedGrid), dim3(256), 0, stream, edst, E, n,
                     cnt, rank, x, W1, bufA);
  hipLaunchKernelGGL(k_scan_block, dim3(B), dim3(1024), 0, stream, cnt, n, rowptr, bsum, dinv);
  hipLaunchKernelGGL(k_scan_top, dim3(1), dim3(128), 0, stream, bsum, boff, B);
  hipLaunchKernelGGL(k_scan_add, dim3((n + 1 + 255) / 256), dim3(256), 0, stream, rowptr, boff, n, E);
  hipLaunchKernelGGL(k_place, dim3((E + 1023) / 1024), dim3(256), 0, stream, esrc, edst, rank, E,
                     rowptr, col);

  // --- layer 1 aggregation: h1 = relu(Â t1 + b1) ---
  hipLaunchKernelGGL((k_agg<64, true, true>), dim3((n + 3) / 4), dim3(256), 0, stream, bufA,
                     rowptr, col, dinv, b1, bufB, n);

  // --- layer 2: g2 = Â h1 ; h2 = relu(g2@W2 + b2) ---
  hipLaunchKernelGGL((k_agg<64, false, false>), dim3((n + 3) / 4), dim3(256), 0, stream, bufB,
                     rowptr, col, dinv, nullptr, bufA, n);
  hipLaunchKernelGGL((k_gemm<64, 128, true, true>), dim3((n + 255) / 256, 4), dim3(256), 0,
                     stream, bufA, W2, b2, bufC, n);

  // --- layer 3: t3 = h2@W3 ; out = Â t3 + b3 ---
  hipLaunchKernelGGL((k_gemm<128, 32, false, false>), dim3((n + 255) / 256, 1), dim3(256), 0,
                     stream, bufC, W3, nullptr, bufA, n);
  hipLaunchKernelGGL((k_agg<32, false, true>), dim3((n + 7) / 8), dim3(256), 0, stream, bufA,
                     rowptr, col, dinv, b3, out, n);

  (void)n_in;
  (void)out_size;
}

// Round 14
// 428.947 us; speedup vs baseline: 1.5648x; 1.2689x over previous
//
#include <hip/hip_runtime.h>
#include <cstdint>
#include <cstddef>

// ---------------------------------------------------------------------------
// GCN 3-layer forward on MI355X.
//   Â = D^-1/2 (A+I) D^-1/2, aggregation on the narrower side (Â(XW)=(ÂX)W):
//   memset cnt=0
//   [fused] rank[e]=atomicAdd(cnt[dst[e]]) ∥ t1 = X@W1       (1:2 block interleave)
//   scan cnt -> rowptr, dinv
//   place: col[rowptr[d]+rank[e]] = src[e]                   (no atomics)
//   h1 = relu(Â t1 + b1); g2 = Â h1; h2 = relu(g2@W2 + b2)
//   t3 = h2@W3; out = Â t3 + b3
// Round-9 evidence: thread-per-row GEMM was fetch-bound (FETCH 346MB vs 26MB
// logical: 64 rows/wave thrash L1, 4x line waste x 4 X-passes from FCHUNK=32).
// Fix: LDS-tiled GEMM -- stage X tile once (coalesced), col-per-lane compute,
// LDS broadcast reads, W loads 1/k/thread. Aggs (MLP-8) validated, unchanged.
// ---------------------------------------------------------------------------

// Per-block exclusive scan of cnt -> rowptr (local), block totals -> bsum.
// Also emits dinv = rsqrt(deg+1).
__global__ __launch_bounds__(1024) void k_scan_block(const int* __restrict__ cnt, int n,
                                                     int* __restrict__ excl,
                                                     int* __restrict__ bsum,
                                                     float* __restrict__ dinv) {
  int tid = threadIdx.x;
  int lane = tid & 63;
  int wid = tid >> 6;
  int gid = blockIdx.x * 1024 + tid;
  int v = (gid < n) ? cnt[gid] : 0;
  if (gid < n) dinv[gid] = rsqrtf((float)v + 1.0f);
  int incl = v;
#pragma unroll
  for (int o = 1; o < 64; o <<= 1) {
    int t = __shfl_up(incl, o, 64);
    if (lane >= o) incl += t;
  }
  __shared__ int wsum[16];
  if (lane == 63) wsum[wid] = incl;
  __syncthreads();
  if (wid == 0) {
    int s = (lane < 16) ? wsum[lane] : 0;
#pragma unroll
    for (int o = 1; o < 16; o <<= 1) {
      int t = __shfl_up(s, o, 64);
      if (lane >= o) s += t;
    }
    if (lane < 16) wsum[lane] = s;
  }
  __syncthreads();
  int off = wid ? wsum[wid - 1] : 0;
  if (gid < n) excl[gid] = off + incl - v;
  if (tid == 1023) bsum[blockIdx.x] = wsum[15];
}

__global__ __launch_bounds__(128) void k_scan_top(const int* __restrict__ bsum,
                                                  int* __restrict__ boff, int B) {
  __shared__ int sm[128];
  int tid = threadIdx.x;
  int v = (tid < B) ? bsum[tid] : 0;
  sm[tid] = v;
  __syncthreads();
  for (int o = 1; o < 128; o <<= 1) {
    int t = (tid >= o) ? sm[tid - o] : 0;
    __syncthreads();
    sm[tid] += t;
    __syncthreads();
  }
  if (tid < B) boff[tid] = sm[tid] - v;
}

__global__ __launch_bounds__(256) void k_scan_add(int* __restrict__ rowptr,
                                                  const int* __restrict__ boff, int n, int E) {
  int i = blockIdx.x * 256 + threadIdx.x;
  if (i < n)
    rowptr[i] += boff[i >> 10];
  else if (i == n)
    rowptr[n] = E;
}

// ---------------------------------------------------------------------------
// LDS-tiled GEMM: Y[n,F] = X[n,K] @ W[K,F] (+bias,+relu).
// Block = 256 threads, tile = ROWS rows. Stage X tile -> LDS once (coalesced
// float4, full-line use). Compute: thread t -> col t%F, row-group t/F of
// R = ROWS/(256/F) rows. LDS reads are same-address broadcasts within a wave
// (no conflicts); W loads: 1 coalesced load per k per thread (K total).
// ---------------------------------------------------------------------------
template <int K, int F, int ROWS, bool RELU, bool BIAS>
__device__ inline void gemm_lds_body(const float* __restrict__ X,
                                     const float* __restrict__ W,
                                     const float* __restrict__ bias,
                                     float* __restrict__ Y, int n, int r0, int tid,
                                     float* __restrict__ xs) {
  constexpr int NG = 256 / F;   // row-groups per block
  constexpr int R = ROWS / NG;  // rows per thread
  const int limit = (n - r0) * K;  // valid flat elements in this tile (>0)
  for (int i = tid * 4; i < ROWS * K; i += 1024) {
    float4 v = make_float4(0.f, 0.f, 0.f, 0.f);
    if (i < limit) v = *reinterpret_cast<const float4*>(X + (size_t)r0 * K + i);
    *reinterpret_cast<float4*>(xs + i) = v;
  }
  __syncthreads();
  const int col = tid % F;
  const int rbase = (tid / F) * R;
  float acc[R];
#pragma unroll
  for (int r = 0; r < R; ++r) acc[r] = 0.f;
  for (int k = 0; k < K; k += 4) {
    float w0 = W[(size_t)(k + 0) * F + col];
    float w1 = W[(size_t)(k + 1) * F + col];
    float w2 = W[(size_t)(k + 2) * F + col];
    float w3 = W[(size_t)(k + 3) * F + col];
#pragma unroll
    for (int r = 0; r < R; ++r) {
      float4 x4 = *reinterpret_cast<const float4*>(xs + (rbase + r) * K + k);
      acc[r] = fmaf(x4.w, w3, fmaf(x4.z, w2, fmaf(x4.y, w1, fmaf(x4.x, w0, acc[r]))));
    }
  }
  const float bv = BIAS ? bias[col] : 0.f;
#pragma unroll
  for (int r = 0; r < R; ++r) {
    int row = r0 + rbase + r;
    if (row < n) {
      float a = acc[r] + bv;
      if (RELU) a = fmaxf(a, 0.f);
      Y[(size_t)row * F + col] = a;  // lanes cover F consecutive cols: coalesced
    }
  }
}

template <int K, int F, int ROWS, bool RELU, bool BIAS>
__global__ __launch_bounds__(256) void k_gemm(const float* __restrict__ X,
                                              const float* __restrict__ W,
                                              const float* __restrict__ bias,
                                              float* __restrict__ Y, int n) {
  __shared__ float xs[ROWS * K];
  int r0 = blockIdx.x * ROWS;
  if (r0 >= n) return;  // block-uniform, before any barrier
  gemm_lds_body<K, F, ROWS, RELU, BIAS>(X, W, bias, Y, n, r0, (int)threadIdx.x, xs);
}

// Fused: period-3 block interleave. r==0: atomic rank pass (4 edges/thread,
// int4); r in {1,2}: GEMM1 32-row LDS tile. At n=100k/E=1.6M both sides need
// exactly 1563 periods. 16KB LDS keeps 8 blocks/CU (not occupancy-limiting).
template <int K, int F>
__global__ __launch_bounds__(256) void k_rank_gemm(const int* __restrict__ edst, int E, int n,
                                                   int* __restrict__ cnt, int* __restrict__ rank,
                                                   const float* __restrict__ X,
                                                   const float* __restrict__ W,
                                                   float* __restrict__ Y) {
  __shared__ float xs[32 * K];
  int bid = blockIdx.x;
  int r = bid % 3;
  int p = bid / 3;
  int tid = threadIdx.x;
  if (r == 0) {
    int e0 = (p * 256 + tid) * 4;
    if (e0 + 3 < E) {
      int4 d4 = *reinterpret_cast<const int4*>(edst + e0);
      int4 rk;
      rk.x = atomicAdd(&cnt[d4.x], 1);
      rk.y = atomicAdd(&cnt[d4.y], 1);
      rk.z = atomicAdd(&cnt[d4.z], 1);
      rk.w = atomicAdd(&cnt[d4.w], 1);
      *reinterpret_cast<int4*>(rank + e0) = rk;
    } else {
      for (int j = 0; j < 4; ++j)
        if (e0 + j < E) rank[e0 + j] = atomicAdd(&cnt[edst[e0 + j]], 1);
    }
  } else {
    int r0 = (p * 2 + (r - 1)) * 32;
    if (r0 >= n) return;  // block-uniform, before any barrier
    gemm_lds_body<K, F, 32, false, false>(X, W, nullptr, Y, n, r0, tid, xs);
  }
}

// Non-atomic placement: col[rowptr[d]+rank[e]] = s. Scattered 4B writes, L2-resident.
__global__ __launch_bounds__(256) void k_place(const int* __restrict__ esrc,
                                               const int* __restrict__ edst,
                                               const int* __restrict__ rank, int E,
                                               const int* __restrict__ rowptr,
                                               int* __restrict__ col) {
  int e0 = (blockIdx.x * 256 + (int)threadIdx.x) * 4;
  if (e0 + 3 < E) {
    int4 s4 = *reinterpret_cast<const int4*>(esrc + e0);
    int4 d4 = *reinterpret_cast<const int4*>(edst + e0);
    int4 r4 = *reinterpret_cast<const int4*>(rank + e0);
    col[rowptr[d4.x] + r4.x] = s4.x;
    col[rowptr[d4.y] + r4.y] = s4.y;
    col[rowptr[d4.z] + r4.z] = s4.z;
    col[rowptr[d4.w] + r4.w] = s4.w;
  } else {
    for (int j = 0; j < 4; ++j)
      if (e0 + j < E) col[rowptr[edst[e0 + j]] + rank[e0 + j]] = esrc[e0 + j];
  }
}

// CSR gather-aggregate, MLP-8 (validated round 9: aggs left the top-5).
template <int F, bool RELU, bool BIAS>
__global__ __launch_bounds__(256) void k_agg(const float* __restrict__ T,
                                             const int* __restrict__ rowptr,
                                             const int* __restrict__ col,
                                             const float* __restrict__ dinv,
                                             const float* __restrict__ bias,
                                             float* __restrict__ Y, int n) {
  constexpr int GPW = 64 / F;  // node groups per wave
  int lane = threadIdx.x & 63;
  int wid = threadIdx.x >> 6;
  int g = lane / F;
  int f = lane % F;
  int node = (blockIdx.x * (int)(blockDim.x >> 6) + wid) * GPW + g;
  if (node >= n) return;  // whole F-lane group exits together
  int base = rowptr[node];
  int deg = rowptr[node + 1] - base;
  float di = dinv[node];
  float acc = T[(size_t)node * F + f] * di * di;
  if (BIAS) acc += bias[f];
  for (int c0 = 0; c0 < deg; c0 += F) {
    int cc = deg - c0;
    if (cc > F) cc = F;
    int myS = 0;
    float myW = 0.0f;
    if (f < cc) {
      myS = col[base + c0 + f];  // coalesced across the group
      myW = dinv[myS] * di;      // parallel gather across lanes
    }
    for (int i = 0; i < cc; i += 8) {
      int ss[8];
      float ww[8];
      float vv[8];
#pragma unroll
      for (int k = 0; k < 8; ++k) {
        ss[k] = __shfl(myS, i + k, F);  // lanes >= cc hold s=0/w=0
        ww[k] = __shfl(myW, i + k, F);
      }
#pragma unroll
      for (int k = 0; k < 8; ++k) vv[k] = T[(size_t)ss[k] * F + f];  // 8 gathers in flight
#pragma unroll
      for (int k = 0; k < 8; ++k) acc += vv[k] * ww[k];
    }
  }
  if (RELU) acc = fmaxf(acc, 0.0f);
  Y[(size_t)node * F + f] = acc;
}

extern "C" void kernel_launch(void* const* d_in, const int* in_sizes, int n_in,
                              void* d_out, int out_size, void* d_ws, size_t ws_size,
                              hipStream_t stream) {
  const float* x = (const float*)d_in[0];
  const int* eidx = (const int*)d_in[1];  // int32: [2,E] flattened (src row, dst row)
  const float* W1 = (const float*)d_in[2];
  const float* b1 = (const float*)d_in[3];
  const float* W2 = (const float*)d_in[4];
  const float* b2 = (const float*)d_in[5];
  const float* W3 = (const float*)d_in[6];
  const float* b3 = (const float*)d_in[7];
  float* out = (float*)d_out;

  const int n = in_sizes[0] / 128;  // 100000 nodes
  const int E = in_sizes[1] / 2;    // 1.6M edges
  const int* esrc = eidx;
  const int* edst = eidx + E;

  // bump allocator over d_ws (re-poisoned every call; all buffers fully rewritten)
  size_t off = 0;
  auto alloc = [&](size_t bytes) {
    size_t o = off;
    off = (off + bytes + 511) & ~(size_t)511;
    return (char*)d_ws + o;
  };
  int* cnt = (int*)alloc((size_t)n * 4);
  int* bsum = (int*)alloc(128 * 4);
  int* boff = (int*)alloc(128 * 4);
  int* rowptr = (int*)alloc((size_t)(n + 1) * 4);
  float* dinv = (float*)alloc((size_t)n * 4);
  int* col = (int*)alloc((size_t)E * 4);
  float* bufA = (float*)alloc((size_t)n * 64 * 4);   // t1 -> g2 -> t3
  float* bufB = (float*)alloc((size_t)n * 64 * 4);   // h1
  float* bufC = (float*)alloc((size_t)n * 128 * 4);  // h2
  int* rank = (int*)bufC;  // lifetime-disjoint overlay: rank dies before gemm2 writes h2
  if (off > ws_size) return;  // visible failure (poisoned d_out), no fault

  const int B = (n + 1023) / 1024;           // scan blocks (98 <= 128)
  const int rankBlocks = (E + 1023) / 1024;  // 4 edges/thread: 1563
  const int gemmTasks = (n + 31) / 32;       // 32-row GEMM1 tiles: 3125
  int periods = rankBlocks;
  if ((gemmTasks + 1) / 2 > periods) periods = (gemmTasks + 1) / 2;
  const int fusedGrid = 3 * periods;  // 4689

  // --- CSR build (pass 1) fused with GEMM1 ---
  hipMemsetAsync(cnt, 0, (size_t)n * 4, stream);
  hipLaunchKernelGGL((k_rank_gemm<128, 64>), dim3(fusedGrid), dim3(256), 0, stream, edst, E, n,
                     cnt, rank, x, W1, bufA);
  hipLaunchKernelGGL(k_scan_block, dim3(B), dim3(1024), 0, stream, cnt, n, rowptr, bsum, dinv);
  hipLaunchKernelGGL(k_scan_top, dim3(1), dim3(128), 0, stream, bsum, boff, B);
  hipLaunchKernelGGL(k_scan_add, dim3((n + 1 + 255) / 256), dim3(256), 0, stream, rowptr, boff, n, E);
  hipLaunchKernelGGL(k_place, dim3((E + 1023) / 1024), dim3(256), 0, stream, esrc, edst, rank, E,
                     rowptr, col);

  // --- layer 1 aggregation: h1 = relu(Â t1 + b1) ---
  hipLaunchKernelGGL((k_agg<64, true, true>), dim3((n + 3) / 4), dim3(256), 0, stream, bufA,
                     rowptr, col, dinv, b1, bufB, n);

  // --- layer 2: g2 = Â h1 ; h2 = relu(g2@W2 + b2) ---
  hipLaunchKernelGGL((k_agg<64, false, false>), dim3((n + 3) / 4), dim3(256), 0, stream, bufB,
                     rowptr, col, dinv, nullptr, bufA, n);
  hipLaunchKernelGGL((k_gemm<64, 128, 64, true, true>), dim3((n + 63) / 64), dim3(256), 0,
                     stream, bufA, W2, b2, bufC, n);

  // --- layer 3: t3 = h2@W3 ; out = Â t3 + b3 ---
  hipLaunchKernelGGL((k_gemm<128, 32, 64, false, false>), dim3((n + 63) / 64), dim3(256), 0,
                     stream, bufC, W3, nullptr, bufA, n);
  hipLaunchKernelGGL((k_agg<32, false, true>), dim3((n + 7) / 8), dim3(256), 0, stream, bufA,
                     rowptr, col, dinv, b3, out, n);

  (void)n_in;
  (void)out_size;
}